// Round 14
// baseline (392.804 us; speedup 1.0000x reference)
//
#include <hip/hip_runtime.h>
#include <hip/hip_cooperative_groups.h>
#include <math.h>

namespace cg = cooperative_groups;

constexpr int BB = 4;
constexpr int NN = 16384;
constexpr int MM = 4096;
constexpr int KK = 8;
constexpr int CC = 64;
constexpr int OO = 128;

// workspace byte offsets
constexpr size_t OFF_IDX   = 0;                                   // int[B*N*K]
constexpr size_t OFF_AT    = OFF_IDX  + (size_t)BB*NN*KK*4;       // float[B*M*C]  A^T  [b][m][o]
constexpr size_t OFF_BVT   = OFF_AT   + (size_t)BB*MM*CC*4;       // float[B*N*C]  Bv^T [b][n][o]
constexpr size_t OFF_CFT   = OFF_BVT  + (size_t)BB*NN*CC*4;       // float[B*M*C]  cf^T [b][m][c]
constexpr size_t OFF_FEAT  = OFF_CFT  + (size_t)BB*MM*CC*4;       // float[B*N*2C] [interp | pf^T]
constexpr size_t OFF_OUTP  = OFF_FEAT + (size_t)BB*NN*2*CC*4;     // (free; cc4 lives here)
constexpr size_t OFF_STATS = OFF_OUTP + (size_t)BB*NN*OO*4;       // floats: see layout in launcher

// unconditional sorted insert of u64 key into ascending kb[0..7] (no-op if key >= kb[7])
__device__ __forceinline__ void insert8(unsigned long long (&kb)[8], unsigned long long k) {
  bool c0 = k < kb[0], c1 = k < kb[1], c2 = k < kb[2], c3 = k < kb[3];
  bool c4 = k < kb[4], c5 = k < kb[5], c6 = k < kb[6], c7 = k < kb[7];
  kb[7] = c6 ? kb[6] : (c7 ? k : kb[7]);
  kb[6] = c5 ? kb[5] : (c6 ? k : kb[6]);
  kb[5] = c4 ? kb[4] : (c5 ? k : kb[5]);
  kb[4] = c3 ? kb[3] : (c4 ? k : kb[4]);
  kb[3] = c2 ? kb[2] : (c3 ? k : kb[3]);
  kb[2] = c1 ? kb[1] : (c2 ? k : kb[2]);
  kb[1] = c0 ? kb[0] : (c1 ? k : kb[1]);
  kb[0] = c0 ? k : kb[0];
}

__device__ __forceinline__ unsigned long long make_key(float d2, int j) {
  unsigned int bits = __float_as_uint(d2);
  unsigned int m = bits ^ ((unsigned int)(((int)bits) >> 31) | 0x80000000u);
  return ((unsigned long long)m << 13) | (unsigned int)j;
}

__device__ __forceinline__ float key_d2(unsigned long long k) {
  unsigned int m = (unsigned int)(k >> 13);
  unsigned int bits = (m & 0x80000000u) ? (m & 0x7fffffffu) : ~m;
  return __uint_as_float(bits);
}

// ---------------- kNN v7: 8-slot stacks (trigger cnt>=5), 33 KB LDS -> 4 blocks/CU ----------------
__global__ __launch_bounds__(512, 4) void knn_kernel(const float* __restrict__ pc,
                                                     const float4* __restrict__ cc4,
                                                     int* __restrict__ idx_i,
                                                     float* __restrict__ idx_f) {
  __shared__ unsigned long long stk[8 * 8 * 64];    // 32 KB stacks; reused as merge area
  __shared__ unsigned int thr_s[64];

  const int b = blockIdx.y;
  const int tid = threadIdx.x;
  const int lane = tid & 63;
  const int wv = tid >> 6;                          // 0..7

  unsigned long long* mystack = &stk[wv * (8 * 64) + lane];   // slot stride 64*8B: conflict-free

  const int n = blockIdx.x * 64 + lane;
  const float* pcb = pc + (size_t)b * 3 * NN;
  const float px = pcb[n], py = pcb[NN + n], pz = pcb[2 * NN + n];
  const float pp = __fadd_rn(__fadd_rn(__fmul_rn(px, px), __fmul_rn(py, py)), __fmul_rn(pz, pz));

  if (tid < 64) thr_s[tid] = 0x7F7FFFFFu;           // FLT_MAX bits
  __syncthreads();

  unsigned long long kb[8];
#pragma unroll
  for (int k = 0; k < 8; ++k) kb[k] = 0xFFFFFFFFFFFFFFFFull;

  const float4* cb = cc4 + (size_t)b * MM;
  const int jbase = __builtin_amdgcn_readfirstlane(wv * 512);  // wave-uniform chunk base

  // warm-up: first 32 items of own chunk, direct sorted insert
  for (int jj = 0; jj < 32; ++jj) {
    float4 cj = cb[jbase + jj];
    float t  = fmaf(pz, cj.z, fmaf(py, cj.y, __fmul_rn(px, cj.x)));
    float d2 = fmaf(-2.0f, t, __fadd_rn(pp, cj.w));   // == (pp+c2) - 2t exactly (2t exact)
    insert8(kb, make_key(d2, jbase + jj));
  }
  {
    float t8 = key_d2(kb[7]);
    if (t8 >= 0.0f && t8 <= 3.0e38f) atomicMin(&thr_s[lane], __float_as_uint(t8));
  }
  __syncthreads();
  float thrF = __uint_as_float(thr_s[lane]);
  int cnt = 0;

  for (int jj = 32; jj < 512; jj += 4) {
#pragma unroll
    for (int u = 0; u < 4; ++u) {
      float4 cj = cb[jbase + jj + u];
      float t  = fmaf(pz, cj.z, fmaf(py, cj.y, __fmul_rn(px, cj.x)));
      float d2 = fmaf(-2.0f, t, __fadd_rn(pp, cj.w));
      if (d2 <= thrF) {                       // superset filter; exact order at drain
        mystack[cnt * 64] = make_key(d2, jbase + jj + u);
        cnt++;
      }
    }
    if (__any(cnt >= 5)) {
      while (__ballot(cnt > 0) != 0ull) {
        unsigned long long key = 0xFFFFFFFFFFFFFFFFull;
        if (cnt > 0) { cnt--; key = mystack[cnt * 64]; }
        insert8(kb, key);
      }
      float t8 = key_d2(kb[7]);
      if (t8 >= 0.0f && t8 <= 3.0e38f) atomicMin(&thr_s[lane], __float_as_uint(t8));
      thrF = __uint_as_float(thr_s[lane]);
    }
  }

  // final drain
  while (__ballot(cnt > 0) != 0ull) {
    unsigned long long key = 0xFFFFFFFFFFFFFFFFull;
    if (cnt > 0) { cnt--; key = mystack[cnt * 64]; }
    insert8(kb, key);
  }

  __syncthreads();   // stacks dead; reuse stk as merge area [k][wv][lane]
#pragma unroll
  for (int k = 0; k < 8; ++k) stk[k * 512 + wv * 64 + lane] = kb[k];
  __syncthreads();

  // parallel tree merge: rounds s = 4, 2, 1 (set-union of unique keys, order-independent)
  for (int s = 4; s >= 1; s >>= 1) {
    if (wv < s) {
#pragma unroll
      for (int k = 0; k < 8; ++k) insert8(kb, stk[k * 512 + (wv + s) * 64 + lane]);
      if (s > 1) {
#pragma unroll
        for (int k = 0; k < 8; ++k) stk[k * 512 + wv * 64 + lane] = kb[k];
      }
    }
    __syncthreads();
  }

  if (wv == 0) {
    size_t base = ((size_t)b * NN + n) * KK;
#pragma unroll
    for (int k = 0; k < 8; ++k) {
      int j = (int)(kb[k] & 8191u);
      idx_i[base + k] = j;
      idx_f[base + k] = (float)j;
    }
  }
}

// ---------------- prework: prep (cc4) + cf transpose + fusedAB in one dispatch ----------------
__global__ __launch_bounds__(256) void prework_kernel(const float* __restrict__ cc,
                                                      const float* __restrict__ cf,
                                                      const float* __restrict__ pf,
                                                      const float* __restrict__ w1,
                                                      float4* __restrict__ cc4,
                                                      float* __restrict__ cfT,
                                                      float* __restrict__ AT,
                                                      float* __restrict__ BvT,
                                                      float* __restrict__ feat) {
  __shared__ float t[64][65];
  __shared__ float wl[128][64];
  int tid = threadIdx.x;
  int bx = blockIdx.x;
  int b = blockIdx.y;

  if (bx < 16) {
    int m = bx * 256 + tid;
    const float* ccb = cc + (size_t)b * 3 * MM;
    float x = ccb[m], y = ccb[MM + m], z = ccb[2 * MM + m];
    float c2 = __fadd_rn(__fadd_rn(__fmul_rn(x, x), __fmul_rn(y, y)), __fmul_rn(z, z));
    cc4[(size_t)b * MM + m] = make_float4(x, y, z, c2);
    return;
  }

  if (bx < 80) {
    int x0 = (bx - 16) * 64;
    const float* sb = cf + (size_t)b * CC * MM;
#pragma unroll
    for (int i = 0; i < 16; i++) {
      int e = i * 256 + tid; int c = e >> 6, xl = e & 63;
      t[c][xl] = sb[(size_t)c * MM + x0 + xl];
    }
    __syncthreads();
#pragma unroll
    for (int i = 0; i < 16; i++) {
      int e = i * 256 + tid; int xl = e >> 6, c = e & 63;
      cfT[((size_t)b * MM + x0 + xl) * 64 + c] = t[c][xl];
    }
    return;
  }

  int x0 = (bx - 80) * 64;
  const float* sb = pf + (size_t)b * CC * NN;
#pragma unroll
  for (int i = 0; i < 16; i++) {
    int e = i * 256 + tid; int c = e >> 6, xl = e & 63;
    t[c][xl] = sb[(size_t)c * NN + x0 + xl];
  }
#pragma unroll
  for (int i = 0; i < 32; i++) {
    int e = i * 256 + tid; int cc2 = e >> 6, o = e & 63;
    wl[cc2][o] = w1[o * (2 * CC) + cc2];
  }
  __syncthreads();

#pragma unroll
  for (int i = 0; i < 16; i++) {
    int e = i * 256 + tid; int xl = e >> 6, c = e & 63;
    feat[((size_t)b * NN + x0 + xl) * 128 + 64 + c] = t[c][xl];
  }

  int xg = tid >> 2, og = tid & 3;
  int x = x0 + xg;

  {
    float acc[16];
#pragma unroll
    for (int o = 0; o < 16; o++) acc[o] = 0.f;
    for (int c = 0; c < 64; c++) {
      float pv = t[c][xg];
#pragma unroll
      for (int o = 0; o < 16; o += 4) {
        float4 w4 = *reinterpret_cast<const float4*>(&wl[64 + c][og * 16 + o]);
        acc[o + 0] = fmaf(w4.x, pv, acc[o + 0]);
        acc[o + 1] = fmaf(w4.y, pv, acc[o + 1]);
        acc[o + 2] = fmaf(w4.z, pv, acc[o + 2]);
        acc[o + 3] = fmaf(w4.w, pv, acc[o + 3]);
      }
    }
    float* d = BvT + ((size_t)b * NN + x) * 64 + og * 16;
#pragma unroll
    for (int o = 0; o < 16; o += 4)
      *reinterpret_cast<float4*>(&d[o]) = make_float4(acc[o], acc[o + 1], acc[o + 2], acc[o + 3]);
  }

  if (x0 < MM) {
    float acc[16];
#pragma unroll
    for (int o = 0; o < 16; o++) acc[o] = 0.f;
    for (int c = 0; c < 64; c++) {
      float pv = t[c][xg];
#pragma unroll
      for (int o = 0; o < 16; o += 4) {
        float4 w4 = *reinterpret_cast<const float4*>(&wl[c][og * 16 + o]);
        acc[o + 0] = fmaf(w4.x, pv, acc[o + 0]);
        acc[o + 1] = fmaf(w4.y, pv, acc[o + 1]);
        acc[o + 2] = fmaf(w4.z, pv, acc[o + 2]);
        acc[o + 3] = fmaf(w4.w, pv, acc[o + 3]);
      }
    }
    float* d = AT + ((size_t)b * MM + x) * 64 + og * 16;
#pragma unroll
    for (int o = 0; o < 16; o += 4)
      *reinterpret_cast<float4*>(&d[o]) = make_float4(acc[o], acc[o + 1], acc[o + 2], acc[o + 3]);
  }
}

// ---------------- sim BN stats: block-reduced sum/sumsq per channel ----------------
__global__ __launch_bounds__(256) void simstats_kernel(const int* __restrict__ idx_i,
                                                       const float* __restrict__ AT,
                                                       const float* __restrict__ BvT,
                                                       const float* __restrict__ b1,
                                                       float* __restrict__ gsum,
                                                       float* __restrict__ gsq) {
  __shared__ float lsum[4][64], lsq[4][64];
  int tid = threadIdx.x; int lane = tid & 63; int wv = tid >> 6;
  int gw = blockIdx.x * 4 + wv;          // 4096 waves
  float b1v = b1[lane];
  float s = 0.f, q = 0.f;
  int p0 = gw * 16;                      // 16 points per wave
  for (int t = 0; t < 16; t++) {
    int p = p0 + t; int b = p >> 14;     // N = 16384
    float bv = BvT[(size_t)p * 64 + lane];
    size_t ib = (size_t)p * KK;
#pragma unroll
    for (int k = 0; k < KK; k++) {
      int m = idx_i[ib + k];
      float a = AT[((size_t)b * MM + m) * 64 + lane];
      float h = (a + bv) + b1v;
      s += h; q = fmaf(h, h, q);
    }
  }
  lsum[wv][lane] = s; lsq[wv][lane] = q;
  __syncthreads();
  if (wv == 0) {
    float S = lsum[0][lane] + lsum[1][lane] + lsum[2][lane] + lsum[3][lane];
    float Q = lsq[0][lane] + lsq[1][lane] + lsq[2][lane] + lsq[3][lane];
    atomicAdd(&gsum[lane], S);
    atomicAdd(&gsq[lane], Q);
  }
}

// ---------------- simw v2: BN inline, prefetched gathers, interleaved shuffle chains ----------------
__global__ __launch_bounds__(256) void simw_kernel(const int* __restrict__ idx_i,
                                                   const float* __restrict__ AT,
                                                   const float* __restrict__ BvT,
                                                   const float* __restrict__ cfT,
                                                   const float* __restrict__ b1,
                                                   const float* __restrict__ gsum,
                                                   const float* __restrict__ gsq,
                                                   const float* __restrict__ g1,
                                                   const float* __restrict__ be1,
                                                   const float* __restrict__ w2,
                                                   const float* __restrict__ b2,
                                                   float* __restrict__ wout,
                                                   float* __restrict__ feat) {
  int tid = threadIdx.x; int lane = tid & 63; int wv = tid >> 6;
  int p = blockIdx.x * 4 + wv;           // one wave per point, 65536 waves
  int b = p >> 14;
  const float cntBN = (float)((size_t)BB * NN * KK);
  float mean = gsum[lane] / cntBN;
  float var  = gsq[lane] / cntBN - mean * mean;
  float sc   = g1[lane] / sqrtf(var + 1e-5f);
  float sh   = be1[lane] - mean * sc;
  float b1v = b1[lane], w2v = w2[lane];
  float b2s = b2[0];
  float bv = BvT[(size_t)p * 64 + lane];
  size_t ib = (size_t)p * KK;

  int mI[KK];
#pragma unroll
  for (int k = 0; k < KK; k++) mI[k] = idx_i[ib + k];

  float a[KK], g[KK];
#pragma unroll
  for (int k = 0; k < KK; k++) {
    size_t col = ((size_t)b * MM + mI[k]) * 64 + lane;
    a[k] = AT[col];
    g[k] = cfT[col];
  }

  float v[KK];
#pragma unroll
  for (int k = 0; k < KK; k++) {
    float h = (a[k] + bv) + b1v;
    float r = fmaxf(fmaf(h, sc, sh), 0.f);
    v[k] = r * w2v;
  }
#pragma unroll
  for (int off = 32; off >= 1; off >>= 1) {
#pragma unroll
    for (int k = 0; k < KK; k++) v[k] += __shfl_xor(v[k], off, 64);
  }

  float ic = 0.f, wsum = 0.f, wmine = 0.f;
#pragma unroll
  for (int k = 0; k < KK; k++) {
    float wk = 1.0f / (1.0f + expf(-(v[k] + b2s)));
    wmine = (lane == k) ? wk : wmine;
    wsum += wk;
    ic = fmaf(g[k], wk, ic);
  }
  if (lane < KK) wout[ib + lane] = wmine;
  feat[(size_t)p * 128 + lane] = ic / (wsum + 1e-8f);
}

// ---------------- mlpfinal (cooperative): GEMM+bias+stats | grid.sync | BN+ReLU+transposed store ----
// 512 blocks x 256 thr, 2 tiles/block (64 pts each). acc[2][4][8] lives in registers across sync.
// LDS: ft 33.28K + wl 4K + stats 2K = ~39.4K -> >=2 blocks/CU co-resident (512 total). VGPR ~110.
__global__ __launch_bounds__(256) void mlpfinal_kernel(const float* __restrict__ feat,
                                                       const float* __restrict__ mw,
                                                       const float* __restrict__ mb,
                                                       const float* __restrict__ mg,
                                                       const float* __restrict__ mbe,
                                                       float* __restrict__ gsum,
                                                       float* __restrict__ gsq,
                                                       float* __restrict__ out0) {
  __shared__ float ft[128][65];
  __shared__ float wl[8][128];
  __shared__ float bsum[128], bsq[128];
  __shared__ float sc_s[128], sh_s[128];
  int tid = threadIdx.x;
  int og = tid >> 3, g = tid & 7;
  int o0 = og * 4, n0 = g * 8;

  if (tid < 128) { bsum[tid] = 0.f; bsq[tid] = 0.f; }

  float acc[2][4][8];
  float mb0 = mb[o0], mb1 = mb[o0 + 1], mb2 = mb[o0 + 2], mb3 = mb[o0 + 3];

#pragma unroll
  for (int t = 0; t < 2; ++t) {
    int nb = (blockIdx.x * 2 + t) * 64;
    __syncthreads();                 // ft safe to overwrite (prev tile fully consumed)
#pragma unroll
    for (int i = 0; i < 32; i++) {   // transpose-load, stride 65 -> conflict-free staging
      int e = i * 256 + tid; int c = e & 127, n = e >> 7;
      ft[c][n] = feat[(size_t)(nb + n) * 128 + c];
    }
#pragma unroll
    for (int oi = 0; oi < 4; oi++)
#pragma unroll
      for (int j = 0; j < 8; j++) acc[t][oi][j] = 0.f;

    for (int c0 = 0; c0 < 128; c0 += 8) {
      __syncthreads();
#pragma unroll
      for (int i = 0; i < 4; i++) {  // stage 8x128 weight chunk
        int e = i * 256 + tid; int cc = e >> 7, o = e & 127;
        wl[cc][o] = mw[(size_t)o * 128 + c0 + cc];
      }
      __syncthreads();
#pragma unroll
      for (int cc = 0; cc < 8; cc++) {
        float4 w4 = *reinterpret_cast<const float4*>(&wl[cc][o0]);
        const float* fr = &ft[c0 + cc][n0];
#pragma unroll
        for (int j = 0; j < 8; j++) {
          float fv = fr[j];
          acc[t][0][j] = fmaf(w4.x, fv, acc[t][0][j]);
          acc[t][1][j] = fmaf(w4.y, fv, acc[t][1][j]);
          acc[t][2][j] = fmaf(w4.z, fv, acc[t][2][j]);
          acc[t][3][j] = fmaf(w4.w, fv, acc[t][3][j]);
        }
      }
    }

    float s[4] = {0.f, 0.f, 0.f, 0.f}, q[4] = {0.f, 0.f, 0.f, 0.f};
#pragma unroll
    for (int j = 0; j < 8; j++) {
      acc[t][0][j] += mb0; acc[t][1][j] += mb1;
      acc[t][2][j] += mb2; acc[t][3][j] += mb3;
      s[0] += acc[t][0][j]; q[0] = fmaf(acc[t][0][j], acc[t][0][j], q[0]);
      s[1] += acc[t][1][j]; q[1] = fmaf(acc[t][1][j], acc[t][1][j], q[1]);
      s[2] += acc[t][2][j]; q[2] = fmaf(acc[t][2][j], acc[t][2][j], q[2]);
      s[3] += acc[t][3][j]; q[3] = fmaf(acc[t][3][j], acc[t][3][j], q[3]);
    }
#pragma unroll
    for (int oi = 0; oi < 4; oi++) {
      atomicAdd(&bsum[o0 + oi], s[oi]);
      atomicAdd(&bsq[o0 + oi], q[oi]);
    }
  }
  __syncthreads();
  if (tid < 128) {
    atomicAdd(&gsum[tid], bsum[tid]);
    atomicAdd(&gsq[tid], bsq[tid]);
  }

  cg::this_grid().sync();            // all 512 blocks: stats complete

  if (tid < 128) {
    const float cnt = (float)((size_t)BB * NN);
    float mean = gsum[tid] / cnt;
    float var  = gsq[tid] / cnt - mean * mean;
    float s    = mg[tid] / sqrtf(var + 1e-5f);
    sc_s[tid] = s;
    sh_s[tid] = mbe[tid] - mean * s;
  }
  __syncthreads();

#pragma unroll
  for (int t = 0; t < 2; ++t) {
    int nb = (blockIdx.x * 2 + t) * 64;
    int b = nb / NN;                 // tile lies within one batch (NN % 64 == 0)
    int nl = nb - b * NN + n0;
#pragma unroll
    for (int oi = 0; oi < 4; oi++) {
      float sc = sc_s[o0 + oi], sh = sh_s[o0 + oi];
      float4 v0, v1;
      v0.x = fmaxf(fmaf(acc[t][oi][0], sc, sh), 0.f);
      v0.y = fmaxf(fmaf(acc[t][oi][1], sc, sh), 0.f);
      v0.z = fmaxf(fmaf(acc[t][oi][2], sc, sh), 0.f);
      v0.w = fmaxf(fmaf(acc[t][oi][3], sc, sh), 0.f);
      v1.x = fmaxf(fmaf(acc[t][oi][4], sc, sh), 0.f);
      v1.y = fmaxf(fmaf(acc[t][oi][5], sc, sh), 0.f);
      v1.z = fmaxf(fmaf(acc[t][oi][6], sc, sh), 0.f);
      v1.w = fmaxf(fmaf(acc[t][oi][7], sc, sh), 0.f);
      float* d = out0 + (size_t)b * OO * NN + (size_t)(o0 + oi) * NN + nl;
      *reinterpret_cast<float4*>(d)     = v0;
      *reinterpret_cast<float4*>(d + 4) = v1;
    }
  }
}

extern "C" void kernel_launch(void* const* d_in, const int* in_sizes, int n_in,
                              void* d_out, int out_size, void* d_ws, size_t ws_size,
                              hipStream_t stream) {
  const float* pc  = (const float*)d_in[0];
  const float* cc  = (const float*)d_in[1];
  const float* cf  = (const float*)d_in[2];
  const float* pf  = (const float*)d_in[3];
  const float* w1  = (const float*)d_in[4];
  const float* b1  = (const float*)d_in[5];
  const float* g1  = (const float*)d_in[6];
  const float* be1 = (const float*)d_in[7];
  const float* w2  = (const float*)d_in[8];
  const float* b2  = (const float*)d_in[9];
  const float* mw  = (const float*)d_in[10];
  const float* mb  = (const float*)d_in[11];
  const float* mg  = (const float*)d_in[12];
  const float* mbe = (const float*)d_in[13];

  float* out0   = (float*)d_out;                       // [B,OUT,N]
  float* outpc  = out0  + (size_t)BB * OO * NN;        // [B,3,N]
  float* outidx = outpc + (size_t)BB * 3 * NN;         // [B,N,K] (as float)
  float* outw   = outidx + (size_t)BB * NN * KK;       // [B,N,K]

  char* ws = (char*)d_ws;
  int*   idx_i = (int*)(ws + OFF_IDX);
  float* AT    = (float*)(ws + OFF_AT);
  float* BvT   = (float*)(ws + OFF_BVT);
  float* cfT   = (float*)(ws + OFF_CFT);
  float* feat  = (float*)(ws + OFF_FEAT);
  float* st    = (float*)(ws + OFF_STATS);
  float4* cc4  = (float4*)(ws + OFF_OUTP);             // outp region now permanently free
  // st layout (floats): [0,64) simsum | [64,128) simsq | [128,256) mlpsum | [256,384) mlpsq

  hipMemsetAsync(st, 0, 384 * sizeof(float), stream);
  hipMemcpyAsync(outpc, pc, (size_t)BB * 3 * NN * sizeof(float), hipMemcpyDeviceToDevice, stream);

  prework_kernel<<<dim3(336, BB), 256, 0, stream>>>(cc, cf, pf, w1, cc4, cfT, AT, BvT, feat);
  knn_kernel<<<dim3(NN / 64, BB), 512, 0, stream>>>(pc, cc4, idx_i, outidx);
  simstats_kernel<<<1024, 256, 0, stream>>>(idx_i, AT, BvT, b1, st, st + 64);
  simw_kernel<<<NN * BB / 4, 256, 0, stream>>>(idx_i, AT, BvT, cfT, b1, st, st + 64,
                                               g1, be1, w2, b2, outw, feat);

  const float* featC = feat;
  float* gsum = st + 128;
  float* gsq  = st + 256;
  void* args[] = {(void*)&featC, (void*)&mw, (void*)&mb, (void*)&mg, (void*)&mbe,
                  (void*)&gsum, (void*)&gsq, (void*)&out0};
  hipLaunchCooperativeKernel((const void*)mlpfinal_kernel, dim3(512), dim3(256),
                             args, 0, stream);
}

// Round 15
// 338.787 us; speedup vs baseline: 1.1594x; 1.1594x over previous
//
#include <hip/hip_runtime.h>
#include <math.h>

constexpr int BB = 4;
constexpr int NN = 16384;
constexpr int MM = 4096;
constexpr int KK = 8;
constexpr int CC = 64;
constexpr int OO = 128;

// workspace byte offsets
constexpr size_t OFF_IDX   = 0;                                   // int[B*N*K]
constexpr size_t OFF_AT    = OFF_IDX  + (size_t)BB*NN*KK*4;       // float[B*M*C]  A^T  [b][m][o]
constexpr size_t OFF_BVT   = OFF_AT   + (size_t)BB*MM*CC*4;       // float[B*N*C]  Bv^T [b][n][o]
constexpr size_t OFF_CFT   = OFF_BVT  + (size_t)BB*NN*CC*4;       // float[B*M*C]  cf^T [b][m][c]
constexpr size_t OFF_FEAT  = OFF_CFT  + (size_t)BB*MM*CC*4;       // float[B*N*2C] [interp | pf^T]
constexpr size_t OFF_OUTP  = OFF_FEAT + (size_t)BB*NN*2*CC*4;     // float[B*N*OO] out_pre [b][n][o]
constexpr size_t OFF_STATS = OFF_OUTP + (size_t)BB*NN*OO*4;       // floats: see layout in launcher
// cc4 (float4[B*M], 256 KB) aliases OFF_OUTP: outp is written only later by mlpgemm.

// unconditional sorted insert of u64 key into ascending kb[0..7] (no-op if key >= kb[7])
__device__ __forceinline__ void insert8(unsigned long long (&kb)[8], unsigned long long k) {
  bool c0 = k < kb[0], c1 = k < kb[1], c2 = k < kb[2], c3 = k < kb[3];
  bool c4 = k < kb[4], c5 = k < kb[5], c6 = k < kb[6], c7 = k < kb[7];
  kb[7] = c6 ? kb[6] : (c7 ? k : kb[7]);
  kb[6] = c5 ? kb[5] : (c6 ? k : kb[6]);
  kb[5] = c4 ? kb[4] : (c5 ? k : kb[5]);
  kb[4] = c3 ? kb[3] : (c4 ? k : kb[4]);
  kb[3] = c2 ? kb[2] : (c3 ? k : kb[3]);
  kb[2] = c1 ? kb[1] : (c2 ? k : kb[2]);
  kb[1] = c0 ? kb[0] : (c1 ? k : kb[1]);
  kb[0] = c0 ? k : kb[0];
}

__device__ __forceinline__ unsigned long long make_key(float d2, int j) {
  unsigned int bits = __float_as_uint(d2);
  unsigned int m = bits ^ ((unsigned int)(((int)bits) >> 31) | 0x80000000u);
  return ((unsigned long long)m << 13) | (unsigned int)j;
}

__device__ __forceinline__ float key_d2(unsigned long long k) {
  unsigned int m = (unsigned int)(k >> 13);
  unsigned int bits = (m & 0x80000000u) ? (m & 0x7fffffffu) : ~m;
  return __uint_as_float(bits);
}

// ---------------- kNN v7b: 8-slot stacks (trigger cnt>=5), warm-up 16, tree merge ----------------
// Capacity invariant: after any non-triggering check all lanes cnt<=4; +4 pushes -> max
// write index 7 < 8 slots. SAFE. Warm-up 16 >= 8 inserts -> kb[7] is a real distance.
__global__ __launch_bounds__(512, 4) void knn_kernel(const float* __restrict__ pc,
                                                     const float4* __restrict__ cc4,
                                                     int* __restrict__ idx_i,
                                                     float* __restrict__ idx_f) {
  __shared__ unsigned long long stk[8 * 8 * 64];    // 32 KB stacks; reused as merge area
  __shared__ unsigned int thr_s[64];

  const int b = blockIdx.y;
  const int tid = threadIdx.x;
  const int lane = tid & 63;
  const int wv = tid >> 6;                          // 0..7

  unsigned long long* mystack = &stk[wv * (8 * 64) + lane];   // slot stride 64*8B: conflict-free

  const int n = blockIdx.x * 64 + lane;
  const float* pcb = pc + (size_t)b * 3 * NN;
  const float px = pcb[n], py = pcb[NN + n], pz = pcb[2 * NN + n];
  const float pp = __fadd_rn(__fadd_rn(__fmul_rn(px, px), __fmul_rn(py, py)), __fmul_rn(pz, pz));

  if (tid < 64) thr_s[tid] = 0x7F7FFFFFu;           // FLT_MAX bits
  __syncthreads();

  unsigned long long kb[8];
#pragma unroll
  for (int k = 0; k < 8; ++k) kb[k] = 0xFFFFFFFFFFFFFFFFull;

  const float4* cb = cc4 + (size_t)b * MM;
  const int jbase = __builtin_amdgcn_readfirstlane(wv * 512);  // wave-uniform chunk base

  // warm-up: first 16 items of own chunk, direct sorted insert
  for (int jj = 0; jj < 16; ++jj) {
    float4 cj = cb[jbase + jj];
    float t  = fmaf(pz, cj.z, fmaf(py, cj.y, __fmul_rn(px, cj.x)));
    float d2 = fmaf(-2.0f, t, __fadd_rn(pp, cj.w));   // == (pp+c2) - 2t exactly (2t exact)
    insert8(kb, make_key(d2, jbase + jj));
  }
  {
    float t8 = key_d2(kb[7]);
    if (t8 >= 0.0f && t8 <= 3.0e38f) atomicMin(&thr_s[lane], __float_as_uint(t8));
  }
  __syncthreads();
  float thrF = __uint_as_float(thr_s[lane]);
  int cnt = 0;

  for (int jj = 16; jj < 512; jj += 4) {
#pragma unroll
    for (int u = 0; u < 4; ++u) {
      float4 cj = cb[jbase + jj + u];
      float t  = fmaf(pz, cj.z, fmaf(py, cj.y, __fmul_rn(px, cj.x)));
      float d2 = fmaf(-2.0f, t, __fadd_rn(pp, cj.w));
      if (d2 <= thrF) {                       // superset filter; exact order at drain
        mystack[cnt * 64] = make_key(d2, jbase + jj + u);
        cnt++;
      }
    }
    if (__any(cnt >= 5)) {
      while (__ballot(cnt > 0) != 0ull) {
        unsigned long long key = 0xFFFFFFFFFFFFFFFFull;
        if (cnt > 0) { cnt--; key = mystack[cnt * 64]; }
        insert8(kb, key);
      }
      float t8 = key_d2(kb[7]);
      if (t8 >= 0.0f && t8 <= 3.0e38f) atomicMin(&thr_s[lane], __float_as_uint(t8));
      thrF = __uint_as_float(thr_s[lane]);
    }
  }

  // final drain
  while (__ballot(cnt > 0) != 0ull) {
    unsigned long long key = 0xFFFFFFFFFFFFFFFFull;
    if (cnt > 0) { cnt--; key = mystack[cnt * 64]; }
    insert8(kb, key);
  }

  __syncthreads();   // stacks dead; reuse stk as merge area [k][wv][lane]
#pragma unroll
  for (int k = 0; k < 8; ++k) stk[k * 512 + wv * 64 + lane] = kb[k];
  __syncthreads();

  // parallel tree merge: rounds s = 4, 2, 1 (set-union of unique keys, order-independent)
  for (int s = 4; s >= 1; s >>= 1) {
    if (wv < s) {
#pragma unroll
      for (int k = 0; k < 8; ++k) insert8(kb, stk[k * 512 + (wv + s) * 64 + lane]);
      if (s > 1) {
#pragma unroll
        for (int k = 0; k < 8; ++k) stk[k * 512 + wv * 64 + lane] = kb[k];
      }
    }
    __syncthreads();
  }

  if (wv == 0) {
    size_t base = ((size_t)b * NN + n) * KK;
#pragma unroll
    for (int k = 0; k < 8; ++k) {
      int j = (int)(kb[k] & 8191u);
      idx_i[base + k] = j;
      idx_f[base + k] = (float)j;
    }
  }
}

// ---------------- prework: prep (cc4) + cf transpose + fusedAB in one dispatch ----------------
// grid: x in [0, 336), y = b. x<16: prep; x<80: cf transpose tile; else fusedAB tile.
__global__ __launch_bounds__(256) void prework_kernel(const float* __restrict__ cc,
                                                      const float* __restrict__ cf,
                                                      const float* __restrict__ pf,
                                                      const float* __restrict__ w1,
                                                      float4* __restrict__ cc4,
                                                      float* __restrict__ cfT,
                                                      float* __restrict__ AT,
                                                      float* __restrict__ BvT,
                                                      float* __restrict__ feat) {
  __shared__ float t[64][65];
  __shared__ float wl[128][64];
  int tid = threadIdx.x;
  int bx = blockIdx.x;
  int b = blockIdx.y;

  if (bx < 16) {
    // prep: cc4[b][m] = {x,y,z,|c|^2}, exact arithmetic
    int m = bx * 256 + tid;
    const float* ccb = cc + (size_t)b * 3 * MM;
    float x = ccb[m], y = ccb[MM + m], z = ccb[2 * MM + m];
    float c2 = __fadd_rn(__fadd_rn(__fmul_rn(x, x), __fmul_rn(y, y)), __fmul_rn(z, z));
    cc4[(size_t)b * MM + m] = make_float4(x, y, z, c2);
    return;
  }

  if (bx < 80) {
    // cf transpose: [C][M] -> cfT[b][m][c]
    int x0 = (bx - 16) * 64;
    const float* sb = cf + (size_t)b * CC * MM;
#pragma unroll
    for (int i = 0; i < 16; i++) {
      int e = i * 256 + tid; int c = e >> 6, xl = e & 63;
      t[c][xl] = sb[(size_t)c * MM + x0 + xl];
    }
    __syncthreads();
#pragma unroll
    for (int i = 0; i < 16; i++) {
      int e = i * 256 + tid; int xl = e >> 6, c = e & 63;
      cfT[((size_t)b * MM + x0 + xl) * 64 + c] = t[c][xl];
    }
    return;
  }

  // fusedAB: stage pf tile; write feat[64:128); BvT all x; AT for x<M
  int x0 = (bx - 80) * 64;
  const float* sb = pf + (size_t)b * CC * NN;
#pragma unroll
  for (int i = 0; i < 16; i++) {
    int e = i * 256 + tid; int c = e >> 6, xl = e & 63;
    t[c][xl] = sb[(size_t)c * NN + x0 + xl];
  }
#pragma unroll
  for (int i = 0; i < 32; i++) {
    int e = i * 256 + tid; int cc2 = e >> 6, o = e & 63;
    wl[cc2][o] = w1[o * (2 * CC) + cc2];
  }
  __syncthreads();

  // feat (transposed pf) write
#pragma unroll
  for (int i = 0; i < 16; i++) {
    int e = i * 256 + tid; int xl = e >> 6, c = e & 63;
    feat[((size_t)b * NN + x0 + xl) * 128 + 64 + c] = t[c][xl];
  }

  int xg = tid >> 2, og = tid & 3;
  int x = x0 + xg;

  // BvT
  {
    float acc[16];
#pragma unroll
    for (int o = 0; o < 16; o++) acc[o] = 0.f;
    for (int c = 0; c < 64; c++) {
      float pv = t[c][xg];
#pragma unroll
      for (int o = 0; o < 16; o += 4) {
        float4 w4 = *reinterpret_cast<const float4*>(&wl[64 + c][og * 16 + o]);
        acc[o + 0] = fmaf(w4.x, pv, acc[o + 0]);
        acc[o + 1] = fmaf(w4.y, pv, acc[o + 1]);
        acc[o + 2] = fmaf(w4.z, pv, acc[o + 2]);
        acc[o + 3] = fmaf(w4.w, pv, acc[o + 3]);
      }
    }
    float* d = BvT + ((size_t)b * NN + x) * 64 + og * 16;
#pragma unroll
    for (int o = 0; o < 16; o += 4)
      *reinterpret_cast<float4*>(&d[o]) = make_float4(acc[o], acc[o + 1], acc[o + 2], acc[o + 3]);
  }

  // AT (only blocks whose x-range lies in [0, MM))
  if (x0 < MM) {
    float acc[16];
#pragma unroll
    for (int o = 0; o < 16; o++) acc[o] = 0.f;
    for (int c = 0; c < 64; c++) {
      float pv = t[c][xg];
#pragma unroll
      for (int o = 0; o < 16; o += 4) {
        float4 w4 = *reinterpret_cast<const float4*>(&wl[c][og * 16 + o]);
        acc[o + 0] = fmaf(w4.x, pv, acc[o + 0]);
        acc[o + 1] = fmaf(w4.y, pv, acc[o + 1]);
        acc[o + 2] = fmaf(w4.z, pv, acc[o + 2]);
        acc[o + 3] = fmaf(w4.w, pv, acc[o + 3]);
      }
    }
    float* d = AT + ((size_t)b * MM + x) * 64 + og * 16;
#pragma unroll
    for (int o = 0; o < 16; o += 4)
      *reinterpret_cast<float4*>(&d[o]) = make_float4(acc[o], acc[o + 1], acc[o + 2], acc[o + 3]);
  }
}

// ---------------- sim BN stats: block-reduced sum/sumsq per channel ----------------
__global__ __launch_bounds__(256) void simstats_kernel(const int* __restrict__ idx_i,
                                                       const float* __restrict__ AT,
                                                       const float* __restrict__ BvT,
                                                       const float* __restrict__ b1,
                                                       float* __restrict__ gsum,
                                                       float* __restrict__ gsq) {
  __shared__ float lsum[4][64], lsq[4][64];
  int tid = threadIdx.x; int lane = tid & 63; int wv = tid >> 6;
  int gw = blockIdx.x * 4 + wv;          // 4096 waves
  float b1v = b1[lane];
  float s = 0.f, q = 0.f;
  int p0 = gw * 16;                      // 16 points per wave
  for (int t = 0; t < 16; t++) {
    int p = p0 + t; int b = p >> 14;     // N = 16384
    float bv = BvT[(size_t)p * 64 + lane];
    size_t ib = (size_t)p * KK;
#pragma unroll
    for (int k = 0; k < KK; k++) {
      int m = idx_i[ib + k];
      float a = AT[((size_t)b * MM + m) * 64 + lane];
      float h = (a + bv) + b1v;
      s += h; q = fmaf(h, h, q);
    }
  }
  lsum[wv][lane] = s; lsq[wv][lane] = q;
  __syncthreads();
  if (wv == 0) {                          // one global atomic pair per channel per block
    float S = lsum[0][lane] + lsum[1][lane] + lsum[2][lane] + lsum[3][lane];
    float Q = lsq[0][lane] + lsq[1][lane] + lsq[2][lane] + lsq[3][lane];
    atomicAdd(&gsum[lane], S);
    atomicAdd(&gsq[lane], Q);
  }
}

// ---------------- simw v2: BN inline, prefetched gathers, interleaved shuffle chains ----------------
__global__ __launch_bounds__(256) void simw_kernel(const int* __restrict__ idx_i,
                                                   const float* __restrict__ AT,
                                                   const float* __restrict__ BvT,
                                                   const float* __restrict__ cfT,
                                                   const float* __restrict__ b1,
                                                   const float* __restrict__ gsum,
                                                   const float* __restrict__ gsq,
                                                   const float* __restrict__ g1,
                                                   const float* __restrict__ be1,
                                                   const float* __restrict__ w2,
                                                   const float* __restrict__ b2,
                                                   float* __restrict__ wout,
                                                   float* __restrict__ feat) {
  int tid = threadIdx.x; int lane = tid & 63; int wv = tid >> 6;
  int p = blockIdx.x * 4 + wv;           // one wave per point, 65536 waves
  int b = p >> 14;
  const float cntBN = (float)((size_t)BB * NN * KK);
  float mean = gsum[lane] / cntBN;
  float var  = gsq[lane] / cntBN - mean * mean;
  float sc   = g1[lane] / sqrtf(var + 1e-5f);
  float sh   = be1[lane] - mean * sc;
  float b1v = b1[lane], w2v = w2[lane];
  float b2s = b2[0];
  float bv = BvT[(size_t)p * 64 + lane];
  size_t ib = (size_t)p * KK;

  int mI[KK];
#pragma unroll
  for (int k = 0; k < KK; k++) mI[k] = idx_i[ib + k];

  float a[KK], g[KK];
#pragma unroll
  for (int k = 0; k < KK; k++) {          // 16 independent gathers in flight
    size_t col = ((size_t)b * MM + mI[k]) * 64 + lane;
    a[k] = AT[col];
    g[k] = cfT[col];
  }

  float v[KK];
#pragma unroll
  for (int k = 0; k < KK; k++) {
    float h = (a[k] + bv) + b1v;
    float r = fmaxf(fmaf(h, sc, sh), 0.f);
    v[k] = r * w2v;
  }
#pragma unroll
  for (int off = 32; off >= 1; off >>= 1) {  // 6 rounds x 8 independent shuffles
#pragma unroll
    for (int k = 0; k < KK; k++) v[k] += __shfl_xor(v[k], off, 64);
  }

  float ic = 0.f, wsum = 0.f, wmine = 0.f;
#pragma unroll
  for (int k = 0; k < KK; k++) {
    float wk = 1.0f / (1.0f + expf(-(v[k] + b2s)));
    wmine = (lane == k) ? wk : wmine;
    wsum += wk;
    ic = fmaf(g[k], wk, ic);
  }
  if (lane < KK) wout[ib + lane] = wmine;
  feat[(size_t)p * 128 + lane] = ic / (wsum + 1e-8f);
}

// ---------------- mlpgemm v2b: 64-point tile, ft[c][n] in LDS, 4o x 8n register tile ----------------
__global__ __launch_bounds__(256) void mlpgemm_kernel(const float* __restrict__ feat,
                                                      const float* __restrict__ mw,
                                                      const float* __restrict__ mb,
                                                      float* __restrict__ outp,
                                                      float* __restrict__ gsum,
                                                      float* __restrict__ gsq) {
  __shared__ float ft[128][65];      // feat tile transposed [c][n], pad -> (c+n)%32 banks
  __shared__ float wl[32][128];      // weight chunk [cc][o] (16 KB)
  __shared__ float bsum[128], bsq[128];
  int tid = threadIdx.x;
  int nb = blockIdx.x * 64;          // 1024 blocks

#pragma unroll
  for (int i = 0; i < 32; i++) {     // transpose-load: coalesced along c
    int e = i * 256 + tid; int c = e & 127, n = e >> 7;
    ft[c][n] = feat[(size_t)(nb + n) * 128 + c];
  }
  if (tid < 128) { bsum[tid] = 0.f; bsq[tid] = 0.f; }

  int og = tid >> 3, g = tid & 7;    // 32 o-quads x 8 n-octets
  int o0 = og * 4, n0 = g * 8;

  float acc[4][8];
#pragma unroll
  for (int oi = 0; oi < 4; oi++)
#pragma unroll
    for (int j = 0; j < 8; j++) acc[oi][j] = 0.f;

  for (int c0 = 0; c0 < 128; c0 += 32) {
    __syncthreads();                 // also covers initial ft staging
#pragma unroll
    for (int i = 0; i < 16; i++) {   // 16 iters stage all 32x128 = 4096 entries
      int e = i * 256 + tid; int cc = e >> 7, o = e & 127;
      wl[cc][o] = mw[(size_t)o * 128 + c0 + cc];
    }
    __syncthreads();
#pragma unroll
    for (int cc = 0; cc < 32; cc++) {
      float4 w4 = *reinterpret_cast<const float4*>(&wl[cc][o0]);
      const float* fr = &ft[c0 + cc][n0];
#pragma unroll
      for (int j = 0; j < 8; j++) {
        float fv = fr[j];
        acc[0][j] = fmaf(w4.x, fv, acc[0][j]);
        acc[1][j] = fmaf(w4.y, fv, acc[1][j]);
        acc[2][j] = fmaf(w4.z, fv, acc[2][j]);
        acc[3][j] = fmaf(w4.w, fv, acc[3][j]);
      }
    }
  }

  float mb0 = mb[o0], mb1 = mb[o0 + 1], mb2 = mb[o0 + 2], mb3 = mb[o0 + 3];
  float s[4] = {0.f, 0.f, 0.f, 0.f}, q[4] = {0.f, 0.f, 0.f, 0.f};
#pragma unroll
  for (int j = 0; j < 8; j++) {
    float4 v4;
    v4.x = acc[0][j] + mb0; v4.y = acc[1][j] + mb1;
    v4.z = acc[2][j] + mb2; v4.w = acc[3][j] + mb3;
    *reinterpret_cast<float4*>(&outp[(size_t)(nb + n0 + j) * 128 + o0]) = v4;
    s[0] += v4.x; q[0] = fmaf(v4.x, v4.x, q[0]);
    s[1] += v4.y; q[1] = fmaf(v4.y, v4.y, q[1]);
    s[2] += v4.z; q[2] = fmaf(v4.z, v4.z, q[2]);
    s[3] += v4.w; q[3] = fmaf(v4.w, v4.w, q[3]);
  }
#pragma unroll
  for (int oi = 0; oi < 4; oi++) {   // 8-way LDS contention per address: cheap
    atomicAdd(&bsum[o0 + oi], s[oi]);
    atomicAdd(&bsq[o0 + oi], q[oi]);
  }
  __syncthreads();
  if (tid < 128) {                   // one global atomic pair per channel per block
    atomicAdd(&gsum[tid], bsum[tid]);
    atomicAdd(&gsq[tid], bsq[tid]);
  }
}

// ---------------- final: BN finalize inline + ReLU + transpose [b][n][o] -> [b][o][n] ----------------
__global__ __launch_bounds__(256) void final_kernel(const float* __restrict__ outp,
                                                    const float* __restrict__ gsum,
                                                    const float* __restrict__ gsq,
                                                    const float* __restrict__ mg,
                                                    const float* __restrict__ mbe,
                                                    float* __restrict__ out0) {
  __shared__ float t[128][65];
  __shared__ float sc_s[128], sh_s[128];
  int b = blockIdx.y;
  int n0 = blockIdx.x * 64;
  int tid = threadIdx.x;
  if (tid < 128) {
    const float cnt = (float)((size_t)BB * NN);
    float mean = gsum[tid] / cnt;
    float var  = gsq[tid] / cnt - mean * mean;
    float s    = mg[tid] / sqrtf(var + 1e-5f);
    sc_s[tid] = s;
    sh_s[tid] = mbe[tid] - mean * s;
  }
  __syncthreads();
#pragma unroll
  for (int i = 0; i < 32; i++) {
    int e = i * 256 + tid;
    int o = e & 127, nl = e >> 7;
    float v = outp[((size_t)b * NN + n0 + nl) * 128 + o];
    t[o][nl] = fmaxf(fmaf(v, sc_s[o], sh_s[o]), 0.f);
  }
  __syncthreads();
#pragma unroll
  for (int i = 0; i < 32; i++) {
    int e = i * 256 + tid;
    int nl = e & 63, o = e >> 6;
    out0[(size_t)b * OO * NN + (size_t)o * NN + n0 + nl] = t[o][nl];
  }
}

extern "C" void kernel_launch(void* const* d_in, const int* in_sizes, int n_in,
                              void* d_out, int out_size, void* d_ws, size_t ws_size,
                              hipStream_t stream) {
  const float* pc  = (const float*)d_in[0];
  const float* cc  = (const float*)d_in[1];
  const float* cf  = (const float*)d_in[2];
  const float* pf  = (const float*)d_in[3];
  const float* w1  = (const float*)d_in[4];
  const float* b1  = (const float*)d_in[5];
  const float* g1  = (const float*)d_in[6];
  const float* be1 = (const float*)d_in[7];
  const float* w2  = (const float*)d_in[8];
  const float* b2  = (const float*)d_in[9];
  const float* mw  = (const float*)d_in[10];
  const float* mb  = (const float*)d_in[11];
  const float* mg  = (const float*)d_in[12];
  const float* mbe = (const float*)d_in[13];

  float* out0   = (float*)d_out;                       // [B,OUT,N]
  float* outpc  = out0  + (size_t)BB * OO * NN;        // [B,3,N]
  float* outidx = outpc + (size_t)BB * 3 * NN;         // [B,N,K] (as float)
  float* outw   = outidx + (size_t)BB * NN * KK;       // [B,N,K]

  char* ws = (char*)d_ws;
  int*   idx_i = (int*)(ws + OFF_IDX);
  float* AT    = (float*)(ws + OFF_AT);
  float* BvT   = (float*)(ws + OFF_BVT);
  float* cfT   = (float*)(ws + OFF_CFT);
  float* feat  = (float*)(ws + OFF_FEAT);
  float* outp  = (float*)(ws + OFF_OUTP);
  float* st    = (float*)(ws + OFF_STATS);
  float4* cc4  = (float4*)(ws + OFF_OUTP);             // alias: outp unused until mlpgemm
  // st layout (floats): [0,64) simsum | [64,128) simsq | [128,256) mlpsum | [256,384) mlpsq

  hipMemsetAsync(st, 0, 384 * sizeof(float), stream);
  hipMemcpyAsync(outpc, pc, (size_t)BB * 3 * NN * sizeof(float), hipMemcpyDeviceToDevice, stream);

  prework_kernel<<<dim3(336, BB), 256, 0, stream>>>(cc, cf, pf, w1, cc4, cfT, AT, BvT, feat);
  knn_kernel<<<dim3(NN / 64, BB), 512, 0, stream>>>(pc, cc4, idx_i, outidx);
  simstats_kernel<<<1024, 256, 0, stream>>>(idx_i, AT, BvT, b1, st, st + 64);
  simw_kernel<<<NN * BB / 4, 256, 0, stream>>>(idx_i, AT, BvT, cfT, b1, st, st + 64,
                                               g1, be1, w2, b2, outw, feat);
  mlpgemm_kernel<<<(BB * NN) / 64, 256, 0, stream>>>(feat, mw, mb, outp, st + 128, st + 256);
  final_kernel<<<dim3(NN / 64, BB), 256, 0, stream>>>(outp, st + 128, st + 256, mg, mbe, out0);
}